// Round 7
// baseline (249.099 us; speedup 1.0000x reference)
//
#include <hip/hip_runtime.h>

#define B_N 32
#define C_N 512
#define T_N 4096
#define D_N 128
#define K_N 1024
#define N_N (B_N * T_N)   // 131072

typedef _Float16 f16x8 __attribute__((ext_vector_type(8)));
typedef float    f32x4 __attribute__((ext_vector_type(4)));

// ---------------- workspace layout (bytes) ----------------
#define ZSWZ_OFF 0
#define ESWZ_OFF 67108864
#define ENS_OFF  67895296
#define WSWZ_OFF 68431872
#define PART_OFF 68694016

#define GLL(g, s) __builtin_amdgcn_global_load_lds( \
    (const __attribute__((address_space(1))) unsigned int*)(g), \
    (__attribute__((address_space(3))) unsigned int*)(s), 16, 0, 0)

// ---------------- codebook prep: norms (x4096) + swizzled fp16-split E
__global__ __launch_bounds__(128) void k_eprep(const float* __restrict__ E,
                                               _Float16* __restrict__ eswz,
                                               float* __restrict__ ens) {
  __shared__ float s2[2];
  const int code = blockIdx.x, d = threadIdx.x;
  const float e  = E[(size_t)code * D_N + d];
  const float es = e * 64.f;
  const _Float16 eh = (_Float16)es;
  const _Float16 el = (_Float16)(es - (float)eh);

  float sq = es * es;
  #pragma unroll
  for (int off = 32; off > 0; off >>= 1) sq += __shfl_down(sq, off);
  if ((d & 63) == 0) s2[d >> 6] = sq;
  __syncthreads();
  if (d == 0) ens[code] = s2[0] + s2[1];   // = 4096 * sum(e^2)

  const int kt = code >> 7, mi = (code >> 4) & 7, lrow = code & 15;
  const int lk = (d >> 3) & 3, i = d & 7, cb = d >> 5;
  const size_t tile = (size_t)kt * 12;
  #define PUT(c, v) eswz[(((tile + (c)) * 512 + mi * 64 + lk * 16 + lrow) << 3) + i] = (v)
  PUT(cb, eh);
  PUT(4 + cb, el);
  PUT(8 + cb, eh);
  #undef PUT
}

// ---------------- W prep: frag-layout fp16 split of proj_w (x8 scale)
__global__ __launch_bounds__(256) void k_wprep(const float* __restrict__ W,
                                               _Float16* __restrict__ wswz) {
  const int e = blockIdx.x * 256 + threadIdx.x;   // 65536 elements
  const int d = e >> 9, c = e & 511;
  const float x = W[d * C_N + c] * 8.f;
  const _Float16 h  = (_Float16)x;
  const _Float16 lo = (_Float16)(x - (float)h);
  const int kc = c >> 5, gg = (c >> 3) & 3, j = c & 7;
  const int nf = d >> 4, ll = gg * 16 + (d & 15);
  const size_t base = (size_t)kc * 8192 + ((size_t)nf * 64 + ll) * 8 + j;
  wswz[base]        = h;
  wswz[base + 4096] = lo;
}

// ---------------- projection GEMM via fp16x3 MFMA (unchanged from R3)
__global__ __launch_bounds__(256, 2) void k_projm(const float* __restrict__ z,
                                                  const _Float16* __restrict__ wswz,
                                                  const float* __restrict__ bias,
                                                  f16x8* __restrict__ zswz) {
  __shared__ __align__(16) char lds[65536];

  const int tid = threadIdx.x;
  const int l   = tid & 63, w = tid >> 6;
  const int g   = l >> 4, li = l & 15;
  const int b   = blockIdx.y, t0 = blockIdx.x * 128;
  const float* zb = z + (size_t)b * C_N * T_N + t0;

  float bs[8];
  #pragma unroll
  for (int nf = 0; nf < 8; ++nf) bs[nf] = bias[nf * 16 + li] * 64.f;

  f32x4 acc[2][8];
  #pragma unroll
  for (int mi = 0; mi < 2; ++mi)
    #pragma unroll
    for (int nf = 0; nf < 8; ++nf) acc[mi][nf] = (f32x4)0.f;

  auto stage = [&](int kc, int buf) {
    char* zdst = lds + buf * 16384;
    char* wdst = lds + 32768 + buf * 16384;
    #pragma unroll
    for (int s = 0; s < 4; ++s) {
      const int q = w * 4 + s;                    // wave-uniform
      const unsigned v = q * 64 + l;              // dest float4 slot
      const unsigned u = v ^ (((v >> 8) & 1) << 2);  // bit4^bit10 dword swizzle
      GLL((const char*)zb +
              ((size_t)(kc * 32 + (u >> 5)) * T_N + (size_t)(u & 31) * 4) * 4,
          zdst + q * 1024);
      GLL((const char*)wswz + (size_t)kc * 16384 + q * 1024 + l * 16,
          wdst + q * 1024);
    }
  };

  stage(0, 0);
  __syncthreads();

  int buf = 0;
  for (int kc = 0; kc < 16; ++kc) {
    if (kc + 1 < 16) stage(kc + 1, buf ^ 1);

    const float* zl = (const float*)(lds + buf * 16384);
    const f16x8* wb = (const f16x8*)(lds + 32768 + buf * 16384);

    f16x8 ah[2], al[2];
    #pragma unroll
    for (int mi = 0; mi < 2; ++mi) {
      const int mt = w * 2 + mi;
      const int a0 = (g * 1024 + mt * 16 + li) ^ ((g & 1) << 4);
      #pragma unroll
      for (int j = 0; j < 8; ++j) {
        const float x = zl[a0 + j * 128] * 8.f;
        const _Float16 h = (_Float16)x;
        ah[mi][j] = h;
        al[mi][j] = (_Float16)(x - (float)h);
      }
    }
    f16x8 bh[8], bl[8];
    #pragma unroll
    for (int nf = 0; nf < 8; ++nf) {
      bh[nf] = wb[nf * 64 + l];
      bl[nf] = wb[512 + nf * 64 + l];
    }
    #pragma unroll
    for (int mi = 0; mi < 2; ++mi)
      #pragma unroll
      for (int nf = 0; nf < 8; ++nf) {
        acc[mi][nf] = __builtin_amdgcn_mfma_f32_16x16x32_f16(ah[mi], bh[nf], acc[mi][nf], 0, 0, 0);
        acc[mi][nf] = __builtin_amdgcn_mfma_f32_16x16x32_f16(al[mi], bh[nf], acc[mi][nf], 0, 0, 0);
        acc[mi][nf] = __builtin_amdgcn_mfma_f32_16x16x32_f16(ah[mi], bl[nf], acc[mi][nf], 0, 0, 0);
      }
    __syncthreads();
    buf ^= 1;
  }

  unsigned* cs = (unsigned*)lds;   // [128][68] uint (hi|lo<<16)
  const int n0 = b * T_N + t0;
  for (int p = 0; p < 2; ++p) {
    #pragma unroll
    for (int mi = 0; mi < 2; ++mi) {
      const int trow = (w * 2 + mi) * 16 + g * 4;
      #pragma unroll
      for (int nfl = 0; nfl < 4; ++nfl) {
        const int nf = p * 4 + nfl;
        #pragma unroll
        for (int r = 0; r < 4; ++r) {
          const float x = acc[mi][nf][r] + bs[nf];
          const _Float16 h  = (_Float16)x;
          const _Float16 lo = (_Float16)(x - (float)h);
          cs[(trow + r) * 68 + nfl * 16 + li] =
              (unsigned)__builtin_bit_cast(unsigned short, h) |
              ((unsigned)__builtin_bit_cast(unsigned short, lo) << 16);
        }
      }
    }
    __syncthreads();
    #pragma unroll
    for (int i = 0; i < 4; ++i) {
      const int u = i * 256 + tid;
      const int t = u & 127, dc = u >> 7;
      f16x8 vh, vl;
      #pragma unroll
      for (int e = 0; e < 8; ++e) {
        const unsigned vv = cs[t * 68 + dc * 8 + e];
        vh[e] = __builtin_bit_cast(_Float16, (unsigned short)(vv & 0xffff));
        vl[e] = __builtin_bit_cast(_Float16, (unsigned short)(vv >> 16));
      }
      const int n = n0 + t;
      const int cu = p * 2 + (dc >> 2), lk = dc & 3;
      const size_t idx = ((size_t)(n >> 4) * 8 + cu) * 64 + lk * 16 + (n & 15);
      zswz[idx]       = vh;
      zswz[idx + 256] = vl;
    }
    __syncthreads();
  }
}

// ---- fused gather epilogue helper: ze read from rows LDS (still resident)
template<int NF0>
__device__ __forceinline__ float gather_lds(int wc, int l, const int* skf,
                                            const float* E, float* ob,
                                            const f16x8* rows) {
  float psum = 0.f;
  #pragma unroll
  for (int nl = 0; nl < 2; ++nl) {
    const int nf = NF0 + nl;
    const int r = wc * 64 + nf * 16 + (l & 15);
    const int k = skf[r];
    const float* Er = E + (size_t)k * D_N;
    #pragma unroll
    for (int cu = 0; cu < 4; ++cu) {
      const int d0 = cu * 32 + (l >> 4) * 8;
      const float4 e0 = *(const float4*)(Er + d0);
      const float4 e1 = *(const float4*)(Er + d0 + 4);
      const float ev[8] = {e0.x, e0.y, e0.z, e0.w, e1.x, e1.y, e1.z, e1.w};
      const f16x8 hi = rows[(((wc * 4 + nf) * 8 + cu) * 64) + l];
      const f16x8 lo = rows[(((wc * 4 + nf) * 8 + cu + 4) * 64) + l];
      #pragma unroll
      for (int j = 0; j < 8; ++j) {
        const float ze = ((float)hi[j] + (float)lo[j]) * 0.015625f;
        const float df = ev[j] - ze;
        psum += df * df;
        ob[(size_t)(d0 + j) * T_N + r] = ev[j];
      }
    }
  }
  return psum;
}

// ---------------- distance GEMM + argmin: R3-verbatim core + fused epilogue
__global__ __launch_bounds__(256, 2) void k_argmin3(const f16x8* __restrict__ zswz,
                                                    const f16x8* __restrict__ eswz,
                                                    const float* __restrict__ ens,
                                                    const float* __restrict__ E,
                                                    float* __restrict__ out,
                                                    float* __restrict__ indf,
                                                    float* __restrict__ part) {
  __shared__ f16x8 rows[4096];     // 64 KB, linear = global layout (kept live)
  __shared__ f16x8 abuf[2][512];   // 2 x 8 KB chunk double-buffer

  const int tid = threadIdx.x;
  const int l   = tid & 63, w = tid >> 6;
  const int wr  = w >> 1, wc = w & 1;
  const int blk = blockIdx.x;

  const char* zsrc = (const char*)zswz + (size_t)blk * 65536;
  #pragma unroll
  for (int s = 0; s < 16; ++s)
    GLL(zsrc + s * 4096 + tid * 16, &rows[s * 256 + w * 64]);

  {
    const char* asrc = (const char*)eswz;
    GLL(asrc + tid * 16,        &abuf[0][w * 64]);
    GLL(asrc + 4096 + tid * 16, &abuf[0][256 + w * 64]);
  }
  __syncthreads();

  float bestd[4];
  int   bestk[4];
  #pragma unroll
  for (int nf = 0; nf < 4; ++nf) { bestd[nf] = 3.4e38f; bestk[nf] = 0; }

  int buf = 0;
  for (int kt = 0; kt < 8; ++kt) {
    f32x4 acc[4][4];
    #pragma unroll
    for (int mi = 0; mi < 4; ++mi)
      #pragma unroll
      for (int nf = 0; nf < 4; ++nf) acc[mi][nf] = (f32x4)0.f;

    for (int c = 0; c < 12; ++c) {
      int nkt = kt, nc = c + 1;
      if (nc == 12) { nc = 0; ++nkt; }
      if (nkt < 8) {
        const char* asrc = (const char*)eswz + ((size_t)(nkt * 12 + nc) * 512) * 16;
        GLL(asrc + tid * 16,        &abuf[buf ^ 1][w * 64]);
        GLL(asrc + 4096 + tid * 16, &abuf[buf ^ 1][256 + w * 64]);
      }
      const int cu = (c < 8) ? (c & 3) : (c - 4);
      f16x8 bfr[4], afr[4];
      #pragma unroll
      for (int nf = 0; nf < 4; ++nf)
        bfr[nf] = rows[((wc * 4 + nf) * 8 + cu) * 64 + l];
      #pragma unroll
      for (int mi = 0; mi < 4; ++mi)
        afr[mi] = abuf[buf][(wr * 4 + mi) * 64 + l];
      #pragma unroll
      for (int mi = 0; mi < 4; ++mi)
        #pragma unroll
        for (int nf = 0; nf < 4; ++nf)
          acc[mi][nf] = __builtin_amdgcn_mfma_f32_16x16x32_f16(
              afr[mi], bfr[nf], acc[mi][nf], 0, 0, 0);
      __syncthreads();
      buf ^= 1;
    }

    #pragma unroll
    for (int mi = 0; mi < 4; ++mi) {
      const int cbase = kt * 128 + wr * 64 + mi * 16 + ((l >> 4) << 2);
      const float4 e4 = *(const float4*)&ens[cbase];
      const float ev[4] = {e4.x, e4.y, e4.z, e4.w};
      #pragma unroll
      for (int r = 0; r < 4; ++r) {
        const int k = cbase + r;
        #pragma unroll
        for (int nf = 0; nf < 4; ++nf) {
          const float dv = ev[r] - 2.0f * acc[mi][nf][r];
          if (dv < bestd[nf]) { bestd[nf] = dv; bestk[nf] = k; }
        }
      }
    }
  }

  // ---- reduce (R3 structure); scratch lives in abuf (dead), rows preserved
  float* sdl = (float*)abuf;
  int*   skl = (int*)((float*)abuf + 256);
  int*   skf = (int*)((float*)abuf + 512);
  #pragma unroll
  for (int nf = 0; nf < 4; ++nf) {
    float d = bestd[nf]; int k = bestk[nf];
    #pragma unroll
    for (int off = 16; off < 64; off <<= 1) {
      const float od = __shfl_xor(d, off);
      const int   ok = __shfl_xor(k, off);
      if (od < d || (od == d && ok < k)) { d = od; k = ok; }
    }
    if (l < 16) {
      sdl[wr * 128 + wc * 64 + nf * 16 + l] = d;
      skl[wr * 128 + wc * 64 + nf * 16 + l] = k;
    }
  }
  __syncthreads();
  if (tid < 128) {
    float d0 = sdl[tid], d1 = sdl[128 + tid];
    int   k0 = skl[tid], k1 = skl[128 + tid];
    if (d1 < d0 || (d1 == d0 && k1 < k0)) { d0 = d1; k0 = k1; }
    skf[tid] = k0;
    indf[blk * 128 + tid] = (float)k0;
  }
  __syncthreads();

  // ---- fused gather: E[ind] -> out[B,D,T]; diff partial from rows LDS ze
  const int b  = blk >> 5;
  const int t0 = (blk & 31) << 7;
  float* ob = out + (size_t)b * (D_N * T_N) + t0;
  float psum = (wr == 0) ? gather_lds<0>(wc, l, skf, E, ob, rows)
                         : gather_lds<2>(wc, l, skf, E, ob, rows);
  #pragma unroll
  for (int off = 32; off > 0; off >>= 1) psum += __shfl_xor(psum, off);
  if (l == 0) part[blk * 4 + w] = psum;
}

// ---------------- final deterministic diff reduction ----------------
__global__ __launch_bounds__(256) void k_diff(const float* __restrict__ part,
                                              float* __restrict__ diff_out) {
  __shared__ double wsd[4];
  const int tid = threadIdx.x;
  double s = 0.0;
  for (int i = tid; i < 4096; i += 256) s += (double)part[i];
  #pragma unroll
  for (int off = 32; off > 0; off >>= 1) s += __shfl_down(s, off);
  if ((tid & 63) == 0) wsd[tid >> 6] = s;
  __syncthreads();
  if (tid == 0) {
    const double tot = wsd[0] + wsd[1] + wsd[2] + wsd[3];
    diff_out[0] = (float)(12.5 * tot / (double)((size_t)N_N * D_N));
  }
}

extern "C" void kernel_launch(void* const* d_in, const int* in_sizes, int n_in,
                              void* d_out, int out_size, void* d_ws, size_t ws_size,
                              hipStream_t stream) {
  const float* z    = (const float*)d_in[0];  // [B, C, T]
  const float* W    = (const float*)d_in[1];  // [D, C]
  const float* bias = (const float*)d_in[2];  // [D]
  const float* E    = (const float*)d_in[3];  // [K, D]

  float* out = (float*)d_out;
  float* out_q    = out;                 // [B, D, T]
  float* out_diff = out + 16777216;      // scalar
  float* out_ind  = out + 16777217;      // [B, T] as float

  char* ws = (char*)d_ws;
  f16x8*    zswz = (f16x8*)(ws + ZSWZ_OFF);
  _Float16* eswz = (_Float16*)(ws + ESWZ_OFF);
  float*    ens  = (float*)(ws + ENS_OFF);
  _Float16* wswz = (_Float16*)(ws + WSWZ_OFF);
  float*    part = (float*)(ws + PART_OFF);

  k_eprep<<<K_N, 128, 0, stream>>>(E, eswz, ens);
  k_wprep<<<256, 256, 0, stream>>>(W, wswz);
  k_projm<<<dim3(T_N / 128, B_N), 256, 0, stream>>>(z, wswz, bias, zswz);
  k_argmin3<<<N_N / 128, 256, 0, stream>>>(zswz, (const f16x8*)eswz, ens, E,
                                           out_q, out_ind, part);
  k_diff<<<1, 256, 0, stream>>>(part, out_diff);
}

// Round 8
// 240.240 us; speedup vs baseline: 1.0369x; 1.0369x over previous
//
#include <hip/hip_runtime.h>

#define B_N 32
#define C_N 512
#define T_N 4096
#define D_N 128
#define K_N 1024
#define N_N (B_N * T_N)   // 131072

typedef _Float16 f16x8 __attribute__((ext_vector_type(8)));
typedef float    f32x4 __attribute__((ext_vector_type(4)));

// ---------------- workspace layout (bytes) ----------------
#define ZSWZ_OFF 0
#define ESWZ_OFF 67108864
#define ENS_OFF  67895296
#define WSWZ_OFF 68431872
#define PART_OFF 68694016

#define GLL(g, s) __builtin_amdgcn_global_load_lds( \
    (const __attribute__((address_space(1))) unsigned int*)(g), \
    (__attribute__((address_space(3))) unsigned int*)(s), 16, 0, 0)

// ---------------- codebook prep: norms (x4096) + swizzled fp16-split E
__global__ __launch_bounds__(128) void k_eprep(const float* __restrict__ E,
                                               _Float16* __restrict__ eswz,
                                               float* __restrict__ ens) {
  __shared__ float s2[2];
  const int code = blockIdx.x, d = threadIdx.x;
  const float e  = E[(size_t)code * D_N + d];
  const float es = e * 64.f;
  const _Float16 eh = (_Float16)es;
  const _Float16 el = (_Float16)(es - (float)eh);

  float sq = es * es;
  #pragma unroll
  for (int off = 32; off > 0; off >>= 1) sq += __shfl_down(sq, off);
  if ((d & 63) == 0) s2[d >> 6] = sq;
  __syncthreads();
  if (d == 0) ens[code] = s2[0] + s2[1];   // = 4096 * sum(e^2)

  const int kt = code >> 7, mi = (code >> 4) & 7, lrow = code & 15;
  const int lk = (d >> 3) & 3, i = d & 7, cb = d >> 5;
  const size_t tile = (size_t)kt * 12;
  #define PUT(c, v) eswz[(((tile + (c)) * 512 + mi * 64 + lk * 16 + lrow) << 3) + i] = (v)
  PUT(cb, eh);
  PUT(4 + cb, el);
  PUT(8 + cb, eh);
  #undef PUT
}

// ---------------- W prep: frag-layout fp16 split of proj_w (x8 scale)
__global__ __launch_bounds__(256) void k_wprep(const float* __restrict__ W,
                                               _Float16* __restrict__ wswz) {
  const int e = blockIdx.x * 256 + threadIdx.x;   // 65536 elements
  const int d = e >> 9, c = e & 511;
  const float x = W[d * C_N + c] * 8.f;
  const _Float16 h  = (_Float16)x;
  const _Float16 lo = (_Float16)(x - (float)h);
  const int kc = c >> 5, gg = (c >> 3) & 3, j = c & 7;
  const int nf = d >> 4, ll = gg * 16 + (d & 15);
  const size_t base = (size_t)kc * 8192 + ((size_t)nf * 64 + ll) * 8 + j;
  wswz[base]        = h;
  wswz[base + 4096] = lo;
}

// ---------------- projection GEMM via fp16x3 MFMA (unchanged from R3)
__global__ __launch_bounds__(256, 2) void k_projm(const float* __restrict__ z,
                                                  const _Float16* __restrict__ wswz,
                                                  const float* __restrict__ bias,
                                                  f16x8* __restrict__ zswz) {
  __shared__ __align__(16) char lds[65536];

  const int tid = threadIdx.x;
  const int l   = tid & 63, w = tid >> 6;
  const int g   = l >> 4, li = l & 15;
  const int b   = blockIdx.y, t0 = blockIdx.x * 128;
  const float* zb = z + (size_t)b * C_N * T_N + t0;

  float bs[8];
  #pragma unroll
  for (int nf = 0; nf < 8; ++nf) bs[nf] = bias[nf * 16 + li] * 64.f;

  f32x4 acc[2][8];
  #pragma unroll
  for (int mi = 0; mi < 2; ++mi)
    #pragma unroll
    for (int nf = 0; nf < 8; ++nf) acc[mi][nf] = (f32x4)0.f;

  auto stage = [&](int kc, int buf) {
    char* zdst = lds + buf * 16384;
    char* wdst = lds + 32768 + buf * 16384;
    #pragma unroll
    for (int s = 0; s < 4; ++s) {
      const int q = w * 4 + s;                    // wave-uniform
      const unsigned v = q * 64 + l;              // dest float4 slot
      const unsigned u = v ^ (((v >> 8) & 1) << 2);  // bit4^bit10 dword swizzle
      GLL((const char*)zb +
              ((size_t)(kc * 32 + (u >> 5)) * T_N + (size_t)(u & 31) * 4) * 4,
          zdst + q * 1024);
      GLL((const char*)wswz + (size_t)kc * 16384 + q * 1024 + l * 16,
          wdst + q * 1024);
    }
  };

  stage(0, 0);
  __syncthreads();

  int buf = 0;
  for (int kc = 0; kc < 16; ++kc) {
    if (kc + 1 < 16) stage(kc + 1, buf ^ 1);

    const float* zl = (const float*)(lds + buf * 16384);
    const f16x8* wb = (const f16x8*)(lds + 32768 + buf * 16384);

    f16x8 ah[2], al[2];
    #pragma unroll
    for (int mi = 0; mi < 2; ++mi) {
      const int mt = w * 2 + mi;
      const int a0 = (g * 1024 + mt * 16 + li) ^ ((g & 1) << 4);
      #pragma unroll
      for (int j = 0; j < 8; ++j) {
        const float x = zl[a0 + j * 128] * 8.f;
        const _Float16 h = (_Float16)x;
        ah[mi][j] = h;
        al[mi][j] = (_Float16)(x - (float)h);
      }
    }
    f16x8 bh[8], bl[8];
    #pragma unroll
    for (int nf = 0; nf < 8; ++nf) {
      bh[nf] = wb[nf * 64 + l];
      bl[nf] = wb[512 + nf * 64 + l];
    }
    #pragma unroll
    for (int mi = 0; mi < 2; ++mi)
      #pragma unroll
      for (int nf = 0; nf < 8; ++nf) {
        acc[mi][nf] = __builtin_amdgcn_mfma_f32_16x16x32_f16(ah[mi], bh[nf], acc[mi][nf], 0, 0, 0);
        acc[mi][nf] = __builtin_amdgcn_mfma_f32_16x16x32_f16(al[mi], bh[nf], acc[mi][nf], 0, 0, 0);
        acc[mi][nf] = __builtin_amdgcn_mfma_f32_16x16x32_f16(ah[mi], bl[nf], acc[mi][nf], 0, 0, 0);
      }
    __syncthreads();
    buf ^= 1;
  }

  unsigned* cs = (unsigned*)lds;   // [128][68] uint (hi|lo<<16)
  const int n0 = b * T_N + t0;
  for (int p = 0; p < 2; ++p) {
    #pragma unroll
    for (int mi = 0; mi < 2; ++mi) {
      const int trow = (w * 2 + mi) * 16 + g * 4;
      #pragma unroll
      for (int nfl = 0; nfl < 4; ++nfl) {
        const int nf = p * 4 + nfl;
        #pragma unroll
        for (int r = 0; r < 4; ++r) {
          const float x = acc[mi][nf][r] + bs[nf];
          const _Float16 h  = (_Float16)x;
          const _Float16 lo = (_Float16)(x - (float)h);
          cs[(trow + r) * 68 + nfl * 16 + li] =
              (unsigned)__builtin_bit_cast(unsigned short, h) |
              ((unsigned)__builtin_bit_cast(unsigned short, lo) << 16);
        }
      }
    }
    __syncthreads();
    #pragma unroll
    for (int i = 0; i < 4; ++i) {
      const int u = i * 256 + tid;
      const int t = u & 127, dc = u >> 7;
      f16x8 vh, vl;
      #pragma unroll
      for (int e = 0; e < 8; ++e) {
        const unsigned vv = cs[t * 68 + dc * 8 + e];
        vh[e] = __builtin_bit_cast(_Float16, (unsigned short)(vv & 0xffff));
        vl[e] = __builtin_bit_cast(_Float16, (unsigned short)(vv >> 16));
      }
      const int n = n0 + t;
      const int cu = p * 2 + (dc >> 2), lk = dc & 3;
      const size_t idx = ((size_t)(n >> 4) * 8 + cu) * 64 + lk * 16 + (n & 15);
      zswz[idx]       = vh;
      zswz[idx + 256] = vl;
    }
    __syncthreads();
  }
}

// ---- fused gather epilogue helper: ze read from rows LDS (still resident)
template<int NF0>
__device__ __forceinline__ float gather_lds(int wc, int l, const int* skf,
                                            const float* E, float* ob,
                                            const f16x8* rows) {
  float psum = 0.f;
  #pragma unroll
  for (int nl = 0; nl < 2; ++nl) {
    const int nf = NF0 + nl;
    const int r = wc * 64 + nf * 16 + (l & 15);
    const int k = skf[r];
    const float* Er = E + (size_t)k * D_N;
    #pragma unroll
    for (int cu = 0; cu < 4; ++cu) {
      const int d0 = cu * 32 + (l >> 4) * 8;
      const float4 e0 = *(const float4*)(Er + d0);
      const float4 e1 = *(const float4*)(Er + d0 + 4);
      const float ev[8] = {e0.x, e0.y, e0.z, e0.w, e1.x, e1.y, e1.z, e1.w};
      const f16x8 hi = rows[(((wc * 4 + nf) * 8 + cu) * 64) + l];
      const f16x8 lo = rows[(((wc * 4 + nf) * 8 + cu + 4) * 64) + l];
      #pragma unroll
      for (int j = 0; j < 8; ++j) {
        const float ze = ((float)hi[j] + (float)lo[j]) * 0.015625f;
        const float df = ev[j] - ze;
        psum += df * df;
        ob[(size_t)(d0 + j) * T_N + r] = ev[j];
      }
    }
  }
  return psum;
}

// ---------------- distance GEMM + argmin: R7 core, B-fragments in registers
__global__ __launch_bounds__(256, 2) void k_argmin3(const f16x8* __restrict__ zswz,
                                                    const f16x8* __restrict__ eswz,
                                                    const float* __restrict__ ens,
                                                    const float* __restrict__ E,
                                                    float* __restrict__ out,
                                                    float* __restrict__ indf,
                                                    float* __restrict__ part) {
  __shared__ f16x8 rows[4096];     // 64 KB, linear = global layout (kept live)
  __shared__ f16x8 abuf[2][512];   // 2 x 8 KB chunk double-buffer

  const int tid = threadIdx.x;
  const int l   = tid & 63, w = tid >> 6;
  const int wr  = w >> 1, wc = w & 1;
  const int blk = blockIdx.x;

  const char* zsrc = (const char*)zswz + (size_t)blk * 65536;
  #pragma unroll
  for (int s = 0; s < 16; ++s)
    GLL(zsrc + s * 4096 + tid * 16, &rows[s * 256 + w * 64]);

  {
    const char* asrc = (const char*)eswz;
    GLL(asrc + tid * 16,        &abuf[0][w * 64]);
    GLL(asrc + 4096 + tid * 16, &abuf[0][256 + w * 64]);
  }
  __syncthreads();

  // ---- NEW vs R7: this wave's B-fragments hoisted to registers (once).
  // rows stays resident (gather reads it later); statically indexed below.
  f16x8 bfr[8][4];
  #pragma unroll
  for (int cu = 0; cu < 8; ++cu)
    #pragma unroll
    for (int nf = 0; nf < 4; ++nf)
      bfr[cu][nf] = rows[((wc * 4 + nf) * 8 + cu) * 64 + l];

  float bestd[4];
  int   bestk[4];
  #pragma unroll
  for (int nf = 0; nf < 4; ++nf) { bestd[nf] = 3.4e38f; bestk[nf] = 0; }

  int buf = 0;
  for (int kt = 0; kt < 8; ++kt) {
    f32x4 acc[4][4];
    #pragma unroll
    for (int mi = 0; mi < 4; ++mi)
      #pragma unroll
      for (int nf = 0; nf < 4; ++nf) acc[mi][nf] = (f32x4)0.f;

    #pragma unroll   // c must be compile-time so bfr[cu][nf] stays in registers
    for (int c = 0; c < 12; ++c) {
      int nkt = kt, nc = c + 1;
      if (nc == 12) { nc = 0; ++nkt; }
      if (nkt < 8) {
        const char* asrc = (const char*)eswz + ((size_t)(nkt * 12 + nc) * 512) * 16;
        GLL(asrc + tid * 16,        &abuf[buf ^ 1][w * 64]);
        GLL(asrc + 4096 + tid * 16, &abuf[buf ^ 1][256 + w * 64]);
      }
      const int cu = (c < 8) ? (c & 3) : (c - 4);
      f16x8 afr[4];
      #pragma unroll
      for (int mi = 0; mi < 4; ++mi)
        afr[mi] = abuf[buf][(wr * 4 + mi) * 64 + l];
      #pragma unroll
      for (int mi = 0; mi < 4; ++mi)
        #pragma unroll
        for (int nf = 0; nf < 4; ++nf)
          acc[mi][nf] = __builtin_amdgcn_mfma_f32_16x16x32_f16(
              afr[mi], bfr[cu][nf], acc[mi][nf], 0, 0, 0);
      __syncthreads();
      buf ^= 1;
    }

    #pragma unroll
    for (int mi = 0; mi < 4; ++mi) {
      const int cbase = kt * 128 + wr * 64 + mi * 16 + ((l >> 4) << 2);
      const float4 e4 = *(const float4*)&ens[cbase];
      const float ev[4] = {e4.x, e4.y, e4.z, e4.w};
      #pragma unroll
      for (int r = 0; r < 4; ++r) {
        const int k = cbase + r;
        #pragma unroll
        for (int nf = 0; nf < 4; ++nf) {
          const float dv = ev[r] - 2.0f * acc[mi][nf][r];
          if (dv < bestd[nf]) { bestd[nf] = dv; bestk[nf] = k; }
        }
      }
    }
  }

  // ---- reduce (R7 structure); scratch lives in abuf (dead), rows preserved
  float* sdl = (float*)abuf;
  int*   skl = (int*)((float*)abuf + 256);
  int*   skf = (int*)((float*)abuf + 512);
  #pragma unroll
  for (int nf = 0; nf < 4; ++nf) {
    float d = bestd[nf]; int k = bestk[nf];
    #pragma unroll
    for (int off = 16; off < 64; off <<= 1) {
      const float od = __shfl_xor(d, off);
      const int   ok = __shfl_xor(k, off);
      if (od < d || (od == d && ok < k)) { d = od; k = ok; }
    }
    if (l < 16) {
      sdl[wr * 128 + wc * 64 + nf * 16 + l] = d;
      skl[wr * 128 + wc * 64 + nf * 16 + l] = k;
    }
  }
  __syncthreads();
  if (tid < 128) {
    float d0 = sdl[tid], d1 = sdl[128 + tid];
    int   k0 = skl[tid], k1 = skl[128 + tid];
    if (d1 < d0 || (d1 == d0 && k1 < k0)) { d0 = d1; k0 = k1; }
    skf[tid] = k0;
    indf[blk * 128 + tid] = (float)k0;
  }
  __syncthreads();

  // ---- fused gather: E[ind] -> out[B,D,T]; diff partial from rows LDS ze
  const int b  = blk >> 5;
  const int t0 = (blk & 31) << 7;
  float* ob = out + (size_t)b * (D_N * T_N) + t0;
  float psum = (wr == 0) ? gather_lds<0>(wc, l, skf, E, ob, rows)
                         : gather_lds<2>(wc, l, skf, E, ob, rows);
  #pragma unroll
  for (int off = 32; off > 0; off >>= 1) psum += __shfl_xor(psum, off);
  if (l == 0) part[blk * 4 + w] = psum;
}

// ---------------- final deterministic diff reduction ----------------
__global__ __launch_bounds__(256) void k_diff(const float* __restrict__ part,
                                              float* __restrict__ diff_out) {
  __shared__ double wsd[4];
  const int tid = threadIdx.x;
  double s = 0.0;
  for (int i = tid; i < 4096; i += 256) s += (double)part[i];
  #pragma unroll
  for (int off = 32; off > 0; off >>= 1) s += __shfl_down(s, off);
  if ((tid & 63) == 0) wsd[tid >> 6] = s;
  __syncthreads();
  if (tid == 0) {
    const double tot = wsd[0] + wsd[1] + wsd[2] + wsd[3];
    diff_out[0] = (float)(12.5 * tot / (double)((size_t)N_N * D_N));
  }
}

extern "C" void kernel_launch(void* const* d_in, const int* in_sizes, int n_in,
                              void* d_out, int out_size, void* d_ws, size_t ws_size,
                              hipStream_t stream) {
  const float* z    = (const float*)d_in[0];  // [B, C, T]
  const float* W    = (const float*)d_in[1];  // [D, C]
  const float* bias = (const float*)d_in[2];  // [D]
  const float* E    = (const float*)d_in[3];  // [K, D]

  float* out = (float*)d_out;
  float* out_q    = out;                 // [B, D, T]
  float* out_diff = out + 16777216;      // scalar
  float* out_ind  = out + 16777217;      // [B, T] as float

  char* ws = (char*)d_ws;
  f16x8*    zswz = (f16x8*)(ws + ZSWZ_OFF);
  _Float16* eswz = (_Float16*)(ws + ESWZ_OFF);
  float*    ens  = (float*)(ws + ENS_OFF);
  _Float16* wswz = (_Float16*)(ws + WSWZ_OFF);
  float*    part = (float*)(ws + PART_OFF);

  k_eprep<<<K_N, 128, 0, stream>>>(E, eswz, ens);
  k_wprep<<<256, 256, 0, stream>>>(W, wswz);
  k_projm<<<dim3(T_N / 128, B_N), 256, 0, stream>>>(z, wswz, bias, zswz);
  k_argmin3<<<N_N / 128, 256, 0, stream>>>(zswz, (const f16x8*)eswz, ens, E,
                                           out_q, out_ind, part);
  k_diff<<<1, 256, 0, stream>>>(part, out_diff);
}

// Round 9
// 214.759 us; speedup vs baseline: 1.1599x; 1.1187x over previous
//
#include <hip/hip_runtime.h>

#define B_N 32
#define C_N 512
#define T_N 4096
#define D_N 128
#define K_N 1024
#define N_N (B_N * T_N)   // 131072

typedef _Float16 f16x8 __attribute__((ext_vector_type(8)));
typedef float    f32x4 __attribute__((ext_vector_type(4)));

// ---------------- workspace layout (bytes) ----------------
#define ZSWZ_OFF 0
#define ESWZ_OFF 67108864
#define ENS_OFF  67895296
#define WSWZ_OFF 68431872
#define PART_OFF 68694016

#define GLL(g, s) __builtin_amdgcn_global_load_lds( \
    (const __attribute__((address_space(1))) unsigned int*)(g), \
    (__attribute__((address_space(3))) unsigned int*)(s), 16, 0, 0)

// ---------------- codebook prep: norms (x4096) + swizzled fp16-split E
__global__ __launch_bounds__(128) void k_eprep(const float* __restrict__ E,
                                               _Float16* __restrict__ eswz,
                                               float* __restrict__ ens) {
  __shared__ float s2[2];
  const int code = blockIdx.x, d = threadIdx.x;
  const float e  = E[(size_t)code * D_N + d];
  const float es = e * 64.f;
  const _Float16 eh = (_Float16)es;
  const _Float16 el = (_Float16)(es - (float)eh);

  float sq = es * es;
  #pragma unroll
  for (int off = 32; off > 0; off >>= 1) sq += __shfl_down(sq, off);
  if ((d & 63) == 0) s2[d >> 6] = sq;
  __syncthreads();
  if (d == 0) ens[code] = s2[0] + s2[1];   // = 4096 * sum(e^2)

  const int kt = code >> 7, mi = (code >> 4) & 7, lrow = code & 15;
  const int lk = (d >> 3) & 3, i = d & 7, cb = d >> 5;
  const size_t tile = (size_t)kt * 12;
  #define PUT(c, v) eswz[(((tile + (c)) * 512 + mi * 64 + lk * 16 + lrow) << 3) + i] = (v)
  PUT(cb, eh);
  PUT(4 + cb, el);
  PUT(8 + cb, eh);
  #undef PUT
}

// ---------------- W prep: frag-layout fp16 split of proj_w (x8 scale)
__global__ __launch_bounds__(256) void k_wprep(const float* __restrict__ W,
                                               _Float16* __restrict__ wswz) {
  const int e = blockIdx.x * 256 + threadIdx.x;   // 65536 elements
  const int d = e >> 9, c = e & 511;
  const float x = W[d * C_N + c] * 8.f;
  const _Float16 h  = (_Float16)x;
  const _Float16 lo = (_Float16)(x - (float)h);
  const int kc = c >> 5, gg = (c >> 3) & 3, j = c & 7;
  const int nf = d >> 4, ll = gg * 16 + (d & 15);
  const size_t base = (size_t)kc * 8192 + ((size_t)nf * 64 + ll) * 8 + j;
  wswz[base]        = h;
  wswz[base + 4096] = lo;
}

// ---------------- projection GEMM via fp16x3 MFMA (unchanged from R3)
__global__ __launch_bounds__(256, 2) void k_projm(const float* __restrict__ z,
                                                  const _Float16* __restrict__ wswz,
                                                  const float* __restrict__ bias,
                                                  f16x8* __restrict__ zswz) {
  __shared__ __align__(16) char lds[65536];

  const int tid = threadIdx.x;
  const int l   = tid & 63, w = tid >> 6;
  const int g   = l >> 4, li = l & 15;
  const int b   = blockIdx.y, t0 = blockIdx.x * 128;
  const float* zb = z + (size_t)b * C_N * T_N + t0;

  float bs[8];
  #pragma unroll
  for (int nf = 0; nf < 8; ++nf) bs[nf] = bias[nf * 16 + li] * 64.f;

  f32x4 acc[2][8];
  #pragma unroll
  for (int mi = 0; mi < 2; ++mi)
    #pragma unroll
    for (int nf = 0; nf < 8; ++nf) acc[mi][nf] = (f32x4)0.f;

  auto stage = [&](int kc, int buf) {
    char* zdst = lds + buf * 16384;
    char* wdst = lds + 32768 + buf * 16384;
    #pragma unroll
    for (int s = 0; s < 4; ++s) {
      const int q = w * 4 + s;                    // wave-uniform
      const unsigned v = q * 64 + l;              // dest float4 slot
      const unsigned u = v ^ (((v >> 8) & 1) << 2);  // bit4^bit10 dword swizzle
      GLL((const char*)zb +
              ((size_t)(kc * 32 + (u >> 5)) * T_N + (size_t)(u & 31) * 4) * 4,
          zdst + q * 1024);
      GLL((const char*)wswz + (size_t)kc * 16384 + q * 1024 + l * 16,
          wdst + q * 1024);
    }
  };

  stage(0, 0);
  __syncthreads();

  int buf = 0;
  for (int kc = 0; kc < 16; ++kc) {
    if (kc + 1 < 16) stage(kc + 1, buf ^ 1);

    const float* zl = (const float*)(lds + buf * 16384);
    const f16x8* wb = (const f16x8*)(lds + 32768 + buf * 16384);

    f16x8 ah[2], al[2];
    #pragma unroll
    for (int mi = 0; mi < 2; ++mi) {
      const int mt = w * 2 + mi;
      const int a0 = (g * 1024 + mt * 16 + li) ^ ((g & 1) << 4);
      #pragma unroll
      for (int j = 0; j < 8; ++j) {
        const float x = zl[a0 + j * 128] * 8.f;
        const _Float16 h = (_Float16)x;
        ah[mi][j] = h;
        al[mi][j] = (_Float16)(x - (float)h);
      }
    }
    f16x8 bh[8], bl[8];
    #pragma unroll
    for (int nf = 0; nf < 8; ++nf) {
      bh[nf] = wb[nf * 64 + l];
      bl[nf] = wb[512 + nf * 64 + l];
    }
    #pragma unroll
    for (int mi = 0; mi < 2; ++mi)
      #pragma unroll
      for (int nf = 0; nf < 8; ++nf) {
        acc[mi][nf] = __builtin_amdgcn_mfma_f32_16x16x32_f16(ah[mi], bh[nf], acc[mi][nf], 0, 0, 0);
        acc[mi][nf] = __builtin_amdgcn_mfma_f32_16x16x32_f16(al[mi], bh[nf], acc[mi][nf], 0, 0, 0);
        acc[mi][nf] = __builtin_amdgcn_mfma_f32_16x16x32_f16(ah[mi], bl[nf], acc[mi][nf], 0, 0, 0);
      }
    __syncthreads();
    buf ^= 1;
  }

  unsigned* cs = (unsigned*)lds;   // [128][68] uint (hi|lo<<16)
  const int n0 = b * T_N + t0;
  for (int p = 0; p < 2; ++p) {
    #pragma unroll
    for (int mi = 0; mi < 2; ++mi) {
      const int trow = (w * 2 + mi) * 16 + g * 4;
      #pragma unroll
      for (int nfl = 0; nfl < 4; ++nfl) {
        const int nf = p * 4 + nfl;
        #pragma unroll
        for (int r = 0; r < 4; ++r) {
          const float x = acc[mi][nf][r] + bs[nf];
          const _Float16 h  = (_Float16)x;
          const _Float16 lo = (_Float16)(x - (float)h);
          cs[(trow + r) * 68 + nfl * 16 + li] =
              (unsigned)__builtin_bit_cast(unsigned short, h) |
              ((unsigned)__builtin_bit_cast(unsigned short, lo) << 16);
        }
      }
    }
    __syncthreads();
    #pragma unroll
    for (int i = 0; i < 4; ++i) {
      const int u = i * 256 + tid;
      const int t = u & 127, dc = u >> 7;
      f16x8 vh, vl;
      #pragma unroll
      for (int e = 0; e < 8; ++e) {
        const unsigned vv = cs[t * 68 + dc * 8 + e];
        vh[e] = __builtin_bit_cast(_Float16, (unsigned short)(vv & 0xffff));
        vl[e] = __builtin_bit_cast(_Float16, (unsigned short)(vv >> 16));
      }
      const int n = n0 + t;
      const int cu = p * 2 + (dc >> 2), lk = dc & 3;
      const size_t idx = ((size_t)(n >> 4) * 8 + cu) * 64 + lk * 16 + (n & 15);
      zswz[idx]       = vh;
      zswz[idx + 256] = vl;
    }
    __syncthreads();
  }
}

// ---- gather epilogue from bfr REGISTERS (R6-proven helper)
template<int NF0>
__device__ __forceinline__ float gather_reg(int wc, int l, const int* skf,
                                            const float* E, float* ob,
                                            const f16x8 (&bfr)[8][4]) {
  float psum = 0.f;
  #pragma unroll
  for (int nl = 0; nl < 2; ++nl) {
    constexpr int NFA[2] = {NF0, NF0 + 1};
    const int nf = NFA[nl];
    const int r = wc * 64 + nf * 16 + (l & 15);
    const int k = skf[r];
    const float* Er = E + (size_t)k * D_N;
    #pragma unroll
    for (int cu = 0; cu < 4; ++cu) {
      const int d0 = cu * 32 + (l >> 4) * 8;
      const float4 e0 = *(const float4*)(Er + d0);
      const float4 e1 = *(const float4*)(Er + d0 + 4);
      const float ev[8] = {e0.x, e0.y, e0.z, e0.w, e1.x, e1.y, e1.z, e1.w};
      const f16x8 hi = bfr[cu][nf];
      const f16x8 lo = bfr[cu + 4][nf];
      #pragma unroll
      for (int j = 0; j < 8; ++j) {
        const float ze = ((float)hi[j] + (float)lo[j]) * 0.015625f;
        const float df = ev[j] - ze;
        psum += df * df;
        ob[(size_t)(d0 + j) * T_N + r] = ev[j];
      }
    }
  }
  return psum;
}

// ---------------- distance GEMM + argmin: 4-chunk periods, 24 barriers
// Sync pattern identical in kind to R8: GLL -> __syncthreads (drain) -> read.
// MFMA order byte-identical to R8 (kt asc, c = 0..11, same cu mapping).
__global__ __launch_bounds__(256, 2) void k_argmin4(const f16x8* __restrict__ zswz,
                                                    const f16x8* __restrict__ eswz,
                                                    const float* __restrict__ ens,
                                                    const float* __restrict__ E,
                                                    float* __restrict__ out,
                                                    float* __restrict__ indf,
                                                    float* __restrict__ part) {
  __shared__ __align__(16) char sbuf[65536];  // rows staging -> 2x32KB period bufs
  __shared__ float sdl[256];
  __shared__ int   skl[256];
  __shared__ int   skf[128];

  const int tid = threadIdx.x, l = tid & 63, w = tid >> 6;
  const int wr = w >> 1, wc = w & 1;
  const int blk = blockIdx.x;

  // ---- prologue: stage this block's 128 ze rows (64 KB) into sbuf
  const char* zsrc = (const char*)zswz + (size_t)blk * 65536;
  #pragma unroll
  for (int s = 0; s < 16; ++s)
    GLL(zsrc + s * 4096 + tid * 16, sbuf + s * 4096 + w * 1024);
  asm volatile("s_waitcnt vmcnt(0)" ::: "memory");
  __syncthreads();

  // ---- B fragments to registers (sbuf will be overwritten by the pipeline)
  f16x8 bfr[8][4];
  #pragma unroll
  for (int cu = 0; cu < 8; ++cu)
    #pragma unroll
    for (int nf = 0; nf < 4; ++nf)
      bfr[cu][nf] =
          *(const f16x8*)(sbuf + (((((wc * 4 + nf) * 8 + cu) * 64) + l) << 4));
  __syncthreads();   // all bfr reads done before sbuf is reused

  // ---- issue period 0 (chunks 0..3, 32 KB) into sbuf[0,32768)
  const char* easrc = (const char*)eswz;
  #pragma unroll
  for (int s = 0; s < 4; ++s) {
    GLL(easrc + s * 8192 + tid * 16,        sbuf + s * 8192 + w * 1024);
    GLL(easrc + s * 8192 + 4096 + tid * 16, sbuf + s * 8192 + 4096 + w * 1024);
  }

  float bestd[4];
  int   bestk[4];
  #pragma unroll
  for (int nf = 0; nf < 4; ++nf) { bestd[nf] = 3.4e38f; bestk[nf] = 0; }

  for (int kt = 0; kt < 8; ++kt) {
    f32x4 acc[4][4];
    #pragma unroll
    for (int mi = 0; mi < 4; ++mi)
      #pragma unroll
      for (int nf = 0; nf < 4; ++nf) acc[mi][nf] = (f32x4)0.f;

    #pragma unroll
    for (int pp = 0; pp < 3; ++pp) {
      const int p = kt * 3 + pp;
      char* rbuf = sbuf + (size_t)(p & 1) * 32768;
      char* wbufp = sbuf + (size_t)((p + 1) & 1) * 32768;

      // top barrier: drains period p's GLLs (issued one full period ago)
      __syncthreads();

      // issue next period's 4 chunks into the other half
      if (p + 1 < 24) {
        const size_t nb = (size_t)(p + 1) * 32768;
        #pragma unroll
        for (int s = 0; s < 4; ++s) {
          GLL(easrc + nb + s * 8192 + tid * 16,
              wbufp + s * 8192 + w * 1024);
          GLL(easrc + nb + s * 8192 + 4096 + tid * 16,
              wbufp + s * 8192 + 4096 + w * 1024);
        }
      }

      // compute this period's 4 chunks (c = pp*4+j), EXACT R8 order
      #pragma unroll
      for (int j = 0; j < 4; ++j) {
        constexpr int CUMAP[12] = {0, 1, 2, 3, 0, 1, 2, 3, 4, 5, 6, 7};
        const int c  = pp * 4 + j;
        const int cu = CUMAP[c];
        f16x8 afr[4];
        #pragma unroll
        for (int mi = 0; mi < 4; ++mi)
          afr[mi] = *(const f16x8*)(rbuf + (size_t)j * 8192 +
                                    (((wr * 4 + mi) * 64 + l) << 4));
        #pragma unroll
        for (int mi = 0; mi < 4; ++mi)
          #pragma unroll
          for (int nf = 0; nf < 4; ++nf)
            acc[mi][nf] = __builtin_amdgcn_mfma_f32_16x16x32_f16(
                afr[mi], bfr[cu][nf], acc[mi][nf], 0, 0, 0);
      }
    }

    // fold this kt's 128 codes into running best (same as R8)
    #pragma unroll
    for (int mi = 0; mi < 4; ++mi) {
      const int cbase = kt * 128 + wr * 64 + mi * 16 + ((l >> 4) << 2);
      const float4 e4 = *(const float4*)&ens[cbase];
      const float ev[4] = {e4.x, e4.y, e4.z, e4.w};
      #pragma unroll
      for (int r = 0; r < 4; ++r) {
        const int k = cbase + r;
        #pragma unroll
        for (int nf = 0; nf < 4; ++nf) {
          const float dv = ev[r] - 2.0f * acc[mi][nf][r];
          if (dv < bestd[nf]) { bestd[nf] = dv; bestk[nf] = k; }
        }
      }
    }
  }

  // ---- argmin reduce (R8 structure, separate scratch arrays)
  #pragma unroll
  for (int nf = 0; nf < 4; ++nf) {
    float d = bestd[nf]; int k = bestk[nf];
    #pragma unroll
    for (int off = 16; off < 64; off <<= 1) {
      const float od = __shfl_xor(d, off);
      const int   ok = __shfl_xor(k, off);
      if (od < d || (od == d && ok < k)) { d = od; k = ok; }
    }
    if (l < 16) {
      sdl[wr * 128 + wc * 64 + nf * 16 + l] = d;
      skl[wr * 128 + wc * 64 + nf * 16 + l] = k;
    }
  }
  __syncthreads();
  if (tid < 128) {
    float d0 = sdl[tid], d1 = sdl[128 + tid];
    int   k0 = skl[tid], k1 = skl[128 + tid];
    if (d1 < d0 || (d1 == d0 && k1 < k0)) { d0 = d1; k0 = k1; }
    skf[tid] = k0;
    indf[blk * 128 + tid] = (float)k0;
  }
  __syncthreads();

  // ---- fused gather from bfr registers: E[ind] -> out[B,D,T] + diff partial
  const int b  = blk >> 5;
  const int t0 = (blk & 31) << 7;
  float* ob = out + (size_t)b * (D_N * T_N) + t0;
  float psum = (wr == 0) ? gather_reg<0>(wc, l, skf, E, ob, bfr)
                         : gather_reg<2>(wc, l, skf, E, ob, bfr);
  #pragma unroll
  for (int off = 32; off > 0; off >>= 1) psum += __shfl_xor(psum, off);
  if (l == 0) part[blk * 4 + w] = psum;
}

// ---------------- final deterministic diff reduction ----------------
__global__ __launch_bounds__(256) void k_diff(const float* __restrict__ part,
                                              float* __restrict__ diff_out) {
  __shared__ double wsd[4];
  const int tid = threadIdx.x;
  double s = 0.0;
  for (int i = tid; i < 4096; i += 256) s += (double)part[i];
  #pragma unroll
  for (int off = 32; off > 0; off >>= 1) s += __shfl_down(s, off);
  if ((tid & 63) == 0) wsd[tid >> 6] = s;
  __syncthreads();
  if (tid == 0) {
    const double tot = wsd[0] + wsd[1] + wsd[2] + wsd[3];
    diff_out[0] = (float)(12.5 * tot / (double)((size_t)N_N * D_N));
  }
}

extern "C" void kernel_launch(void* const* d_in, const int* in_sizes, int n_in,
                              void* d_out, int out_size, void* d_ws, size_t ws_size,
                              hipStream_t stream) {
  const float* z    = (const float*)d_in[0];  // [B, C, T]
  const float* W    = (const float*)d_in[1];  // [D, C]
  const float* bias = (const float*)d_in[2];  // [D]
  const float* E    = (const float*)d_in[3];  // [K, D]

  float* out = (float*)d_out;
  float* out_q    = out;                 // [B, D, T]
  float* out_diff = out + 16777216;      // scalar
  float* out_ind  = out + 16777217;      // [B, T] as float

  char* ws = (char*)d_ws;
  f16x8*    zswz = (f16x8*)(ws + ZSWZ_OFF);
  _Float16* eswz = (_Float16*)(ws + ESWZ_OFF);
  float*    ens  = (float*)(ws + ENS_OFF);
  _Float16* wswz = (_Float16*)(ws + WSWZ_OFF);
  float*    part = (float*)(ws + PART_OFF);

  k_eprep<<<K_N, 128, 0, stream>>>(E, eswz, ens);
  k_wprep<<<256, 256, 0, stream>>>(W, wswz);
  k_projm<<<dim3(T_N / 128, B_N), 256, 0, stream>>>(z, wswz, bias, zswz);
  k_argmin4<<<N_N / 128, 256, 0, stream>>>(zswz, (const f16x8*)eswz, ens, E,
                                           out_q, out_ind, part);
  k_diff<<<1, 256, 0, stream>>>(part, out_diff);
}